// Round 1
// baseline (3657.401 us; speedup 1.0000x reference)
//
#include <hip/hip_runtime.h>

// Topology encoder: 2-layer GCN (N=100k nodes, E=3.2M edges) + max/mean pool
// over B=64 graphs + 2-layer MLP. All fp32.
//
// Input order (from setup_inputs):
//  0: x        [N,3]   f32
//  1: edge_idx [2,E]   i32   (row0 = src, row1 = dst)
//  2: batch    [N]     i32   (sorted graph ids in [0,B))
//  3: W1 [3,32] 4: b1[32] 5: W2 [32,32] 6: b2[32]
//  7: LW1[64,64] 8: Lb1[64] 9: LW2[64,OUT] 10: Lb2[OUT]
// Output: [B, OUT] f32.

#define F 32      // GCN feature width
#define POOLD 64  // pooled dim = 2*F

__global__ void k_init(float* __restrict__ deg, float* __restrict__ pools,
                       int n, int poolsz) {
    int i = blockIdx.x * blockDim.x + threadIdx.x;
    if (i < n) deg[i] = 1.0f;           // self-loop contribution to degree
    if (i < poolsz) pools[i] = 0.0f;    // sum/max/cnt accumulators
}

__global__ void k_deg(const int* __restrict__ ei, float* __restrict__ deg, int e) {
    int i = blockIdx.x * blockDim.x + threadIdx.x;
    if (i < e) atomicAdd(&deg[ei[e + i]], 1.0f);   // dst row
}

__global__ void k_dinv(float* __restrict__ deg, int n) {
    int i = blockIdx.x * blockDim.x + threadIdx.x;
    if (i < n) deg[i] = rsqrtf(deg[i]);            // deg >= 1 always
}

// h0[n,f] = sum_k x[n,k] * W1[k,f]   (K=3)
__global__ void k_xw1(const float* __restrict__ x, const float* __restrict__ W1,
                      float* __restrict__ h0, int n) {
    int i = blockIdx.x * blockDim.x + threadIdx.x;
    if (i >= n * F) return;
    int node = i >> 5, f = i & (F - 1);
    float x0 = x[node * 3 + 0], x1 = x[node * 3 + 1], x2 = x[node * 3 + 2];
    h0[i] = x0 * W1[f] + x1 * W1[F + f] + x2 * W1[2 * F + f];
}

// acc[n,f] = src[n,f] * dinv[n]^2   (self-loop message)
__global__ void k_selfinit(const float* __restrict__ src, const float* __restrict__ dinv,
                           float* __restrict__ acc, int n) {
    int i = blockIdx.x * blockDim.x + threadIdx.x;
    if (i >= n * F) return;
    float d = dinv[i >> 5];
    acc[i] = src[i] * d * d;
}

// per real edge: acc[dst,:] += h[src,:] * dinv[src]*dinv[dst]
// one thread handles 4 features of one edge (float4 gather, 4 atomics)
__global__ void k_scatter(const int* __restrict__ ei, const float* __restrict__ dinv,
                          const float* __restrict__ h, float* __restrict__ acc, int e) {
    int t = blockIdx.x * blockDim.x + threadIdx.x;
    if (t >= e * 8) return;
    int edge = t >> 3, q = t & 7;
    int s = ei[edge], d = ei[e + edge];
    float w = dinv[s] * dinv[d];
    const float4 v = *reinterpret_cast<const float4*>(h + s * F + q * 4);
    float* out = acc + d * F + q * 4;
    atomicAdd(out + 0, v.x * w);
    atomicAdd(out + 1, v.y * w);
    atomicAdd(out + 2, v.z * w);
    atomicAdd(out + 3, v.w * w);
}

// v = relu(acc + bias); optionally store back; pool into sum/max (+count)
__global__ void k_finalize(float* __restrict__ acc, const float* __restrict__ bias,
                           const int* __restrict__ batch,
                           float* __restrict__ psum, float* __restrict__ pmax,
                           float* __restrict__ cnt, int n, int store, int do_cnt) {
    int i = blockIdx.x * blockDim.x + threadIdx.x;
    if (i >= n * F) return;
    int node = i >> 5, f = i & (F - 1);
    float v = fmaxf(acc[i] + bias[f], 0.0f);
    if (store) acc[i] = v;
    int b = batch[node];
    atomicAdd(&psum[b * F + f], v);
    atomicMax(reinterpret_cast<int*>(&pmax[b * F + f]), __float_as_int(v)); // v>=0
    if (do_cnt && f == 0) atomicAdd(&cnt[b], 1.0f);
}

// g[n,f] = sum_k h[n,k] * W2[k,f]   (32x32)
__global__ void k_gemm2(const float* __restrict__ h, const float* __restrict__ W2,
                        float* __restrict__ g, int n) {
    int i = blockIdx.x * blockDim.x + threadIdx.x;
    if (i >= n * F) return;
    int node = i >> 5, f = i & (F - 1);
    const float* row = h + node * F;
    float acc = 0.0f;
#pragma unroll
    for (int k = 0; k < F; ++k) acc += row[k] * W2[k * F + f];
    g[i] = acc;
}

// z[b,j] = relu( sum_i s[b,i] * LW1[i,j] + Lb1[j] )
// s[b,i] = (i<32) ? max1+max2 : (sum1+sum2)/max(cnt,1)
__global__ void k_mlp1(const float* __restrict__ sum1, const float* __restrict__ max1,
                       const float* __restrict__ sum2, const float* __restrict__ max2,
                       const float* __restrict__ cnt,
                       const float* __restrict__ LW1, const float* __restrict__ Lb1,
                       float* __restrict__ z, int nb) {
    int t = blockIdx.x * blockDim.x + threadIdx.x;
    if (t >= nb * POOLD) return;
    int b = t >> 6, j = t & (POOLD - 1);
    float invc = 1.0f / fmaxf(cnt[b], 1.0f);
    float acc = Lb1[j];
#pragma unroll
    for (int i = 0; i < POOLD; ++i) {
        float s;
        if (i < F) s = max1[b * F + i] + max2[b * F + i];
        else       s = (sum1[b * F + i - F] + sum2[b * F + i - F]) * invc;
        acc += s * LW1[i * POOLD + j];
    }
    z[t] = fmaxf(acc, 0.0f);
}

// out[b,o] = sum_j z[b,j] * LW2[j,o] + Lb2[o]
__global__ void k_mlp2(const float* __restrict__ z, const float* __restrict__ LW2,
                       const float* __restrict__ Lb2, float* __restrict__ out,
                       int nb, int outd) {
    int t = blockIdx.x * blockDim.x + threadIdx.x;
    if (t >= nb * outd) return;
    int b = t / outd, o = t % outd;
    float acc = Lb2[o];
#pragma unroll
    for (int j = 0; j < POOLD; ++j) acc += z[b * POOLD + j] * LW2[j * outd + o];
    out[t] = acc;
}

extern "C" void kernel_launch(void* const* d_in, const int* in_sizes, int n_in,
                              void* d_out, int out_size, void* d_ws, size_t ws_size,
                              hipStream_t stream) {
    const float* x    = (const float*)d_in[0];
    const int*   ei   = (const int*)d_in[1];
    const int*   batch= (const int*)d_in[2];
    const float* W1   = (const float*)d_in[3];
    const float* b1   = (const float*)d_in[4];
    const float* W2   = (const float*)d_in[5];
    const float* b2   = (const float*)d_in[6];
    const float* LW1  = (const float*)d_in[7];
    const float* Lb1  = (const float*)d_in[8];
    const float* LW2  = (const float*)d_in[9];
    const float* Lb2  = (const float*)d_in[10];
    float* out = (float*)d_out;

    const int N = in_sizes[0] / 3;
    const int E = in_sizes[1] / 2;
    const int OUTD = in_sizes[10];      // 64
    const int B = out_size / OUTD;      // 64

    // workspace layout (floats)
    float* ws = (float*)d_ws;
    float* deg  = ws;                   // [N] -> becomes dinv
    float* buf0 = deg + N;              // [N*F]  h0 / g
    float* buf1 = buf0 + (size_t)N * F; // [N*F]  conv accumulator / h
    float* pools = buf1 + (size_t)N * F;
    float* sum1 = pools;                // [B*F]
    float* max1 = sum1 + B * F;         // [B*F]
    float* sum2 = max1 + B * F;         // [B*F]
    float* max2 = sum2 + B * F;         // [B*F]
    float* cnt  = max2 + B * F;         // [B]
    float* z    = cnt + B;              // [B*POOLD]
    const int poolsz = 4 * B * F + B;

    const int BS = 256;
    auto g1 = [&](long long n) { return (int)((n + BS - 1) / BS); };

    // 1) degree with self-loops, zero pool accumulators
    k_init<<<g1(N > poolsz ? N : poolsz), BS, 0, stream>>>(deg, pools, N, poolsz);
    k_deg<<<g1(E), BS, 0, stream>>>(ei, deg, E);
    k_dinv<<<g1(N), BS, 0, stream>>>(deg, N);

    // 2) layer 1: h0 = x@W1 ; conv ; relu+pool (store h into buf1)
    k_xw1<<<g1((long long)N * F), BS, 0, stream>>>(x, W1, buf0, N);
    k_selfinit<<<g1((long long)N * F), BS, 0, stream>>>(buf0, deg, buf1, N);
    k_scatter<<<g1((long long)E * 8), BS, 0, stream>>>(ei, deg, buf0, buf1, E);
    k_finalize<<<g1((long long)N * F), BS, 0, stream>>>(buf1, b1, batch, sum1, max1,
                                                        cnt, N, /*store=*/1, /*cnt=*/1);

    // 3) layer 2: g = h@W2 ; conv ; relu+pool (no store needed)
    k_gemm2<<<g1((long long)N * F), BS, 0, stream>>>(buf1, W2, buf0, N);
    k_selfinit<<<g1((long long)N * F), BS, 0, stream>>>(buf0, deg, buf1, N);
    k_scatter<<<g1((long long)E * 8), BS, 0, stream>>>(ei, deg, buf0, buf1, E);
    k_finalize<<<g1((long long)N * F), BS, 0, stream>>>(buf1, b2, batch, sum2, max2,
                                                        cnt, N, /*store=*/0, /*cnt=*/0);

    // 4) MLP head
    k_mlp1<<<g1(B * POOLD), BS, 0, stream>>>(sum1, max1, sum2, max2, cnt,
                                             LW1, Lb1, z, B);
    k_mlp2<<<g1(B * OUTD), BS, 0, stream>>>(z, LW2, Lb2, out, B, OUTD);
}

// Round 2
// 665.005 us; speedup vs baseline: 5.4998x; 5.4998x over previous
//
#include <hip/hip_runtime.h>

// Topology encoder: 2-layer GCN (N=100k nodes, E=3.2M edges) + max/mean pool
// over B=64 graphs + 2-layer MLP. All fp32.
//
// Strategy: build CSR-by-dst once per call (hist -> scan -> place), then each
// GCN layer is a GATHER (no fp32 scatter atomics). Gather fuses self-loop,
// bias, ReLU, and pooling (wave-reduced atomics).
//
// Input order:
//  0: x[N,3] 1: edge_idx[2,E] i32 (row0=src,row1=dst) 2: batch[N] i32 sorted
//  3: W1[3,32] 4: b1[32] 5: W2[32,32] 6: b2[32]
//  7: LW1[64,64] 8: Lb1[64] 9: LW2[64,OUT] 10: Lb2[OUT]
// Output: [B, OUT] f32.

#define F 32
#define POOLD 64
#define SCAN_CHUNK 1024   // 256 threads x 4 elements

// ---- init: zero counts + pool accumulators ----
__global__ void k_init(int* __restrict__ counts, float* __restrict__ pools,
                       int n, int poolsz) {
    int i = blockIdx.x * blockDim.x + threadIdx.x;
    if (i < n) counts[i] = 0;
    if (i < poolsz) pools[i] = 0.0f;
}

// ---- degree histogram over dst ----
__global__ void k_hist(const int* __restrict__ ei, int* __restrict__ counts, int e) {
    int i = blockIdx.x * blockDim.x + threadIdx.x;
    if (i < e) atomicAdd(&counts[ei[e + i]], 1);
}

// ---- dinv = rsqrt(deg + selfloop) ----
__global__ void k_dinv(const int* __restrict__ counts, float* __restrict__ dinv, int n) {
    int i = blockIdx.x * blockDim.x + threadIdx.x;
    if (i < n) dinv[i] = rsqrtf((float)counts[i] + 1.0f);
}

// ---- two-level exclusive scan of counts -> rowptr ----
__global__ void k_scan1(const int* __restrict__ cnts, int* __restrict__ rp,
                        int* __restrict__ partial, int n) {
    __shared__ int lds[256];
    int base = blockIdx.x * SCAN_CHUNK;
    int t = threadIdx.x;
    int v[4];
    int s = 0;
#pragma unroll
    for (int j = 0; j < 4; ++j) {
        int i = base + t * 4 + j;
        v[j] = (i < n) ? cnts[i] : 0;
        s += v[j];
    }
    lds[t] = s;
    __syncthreads();
    int val = s;
    for (int off = 1; off < 256; off <<= 1) {
        int other = (t >= off) ? lds[t - off] : 0;
        __syncthreads();
        val += other;
        lds[t] = val;
        __syncthreads();
    }
    int excl = val - s;  // exclusive prefix of this thread's 4-chunk
#pragma unroll
    for (int j = 0; j < 4; ++j) {
        int i = base + t * 4 + j;
        if (i < n) rp[i] = excl;
        excl += v[j];
    }
    if (t == 255) partial[blockIdx.x] = lds[255];
}

__global__ void k_scan2(int* __restrict__ partial, int nb) {
    __shared__ int lds[256];
    int t = threadIdx.x;
    int s = (t < nb) ? partial[t] : 0;
    lds[t] = s;
    __syncthreads();
    int val = s;
    for (int off = 1; off < 256; off <<= 1) {
        int other = (t >= off) ? lds[t - off] : 0;
        __syncthreads();
        val += other;
        lds[t] = val;
        __syncthreads();
    }
    if (t < nb) partial[t] = val - s;  // exclusive
}

__global__ void k_scan3(int* __restrict__ rp, const int* __restrict__ partial, int n) {
    int base = blockIdx.x * SCAN_CHUNK;
    int add = partial[blockIdx.x];
    int t = threadIdx.x;
#pragma unroll
    for (int j = 0; j < 4; ++j) {
        int i = base + t * 4 + j;
        if (i < n) rp[i] += add;
    }
}

// ---- CSR placement: col[slot] = src. rowptr[d] mutates from start to end. ----
__global__ void k_place(const int* __restrict__ ei, int* __restrict__ rp,
                        int* __restrict__ col, int e) {
    int i = blockIdx.x * blockDim.x + threadIdx.x;
    if (i >= e) return;
    int s = ei[i], d = ei[e + i];
    int p = atomicAdd(&rp[d], 1);
    col[p] = s;
}

// ---- h0 = x @ W1  (K=3) ----
__global__ void k_xw1(const float* __restrict__ x, const float* __restrict__ W1,
                      float* __restrict__ h0, int n) {
    int i = blockIdx.x * blockDim.x + threadIdx.x;
    if (i >= n * F) return;
    int node = i >> 5, f = i & (F - 1);
    float x0 = x[node * 3 + 0], x1 = x[node * 3 + 1], x2 = x[node * 3 + 2];
    h0[i] = x0 * W1[f] + x1 * W1[F + f] + x2 * W1[2 * F + f];
}

// ---- g = h @ W2  (32x32) ----
__global__ void k_gemm2(const float* __restrict__ h, const float* __restrict__ W2,
                        float* __restrict__ g, int n) {
    int i = blockIdx.x * blockDim.x + threadIdx.x;
    if (i >= n * F) return;
    int node = i >> 5, f = i & (F - 1);
    const float* row = h + node * F;
    float acc = 0.0f;
#pragma unroll
    for (int k = 0; k < F; ++k) acc += row[k] * W2[k * F + f];
    g[i] = acc;
}

// ---- fused gather conv + bias + relu + pool ----
// 8 threads per node (each owns 4 features). Row range of node d is
// [d==0 ? 0 : rp[d-1], rp[d]) because k_place turned rp into row ENDS.
__global__ void k_gather(const float* __restrict__ hin, const int* __restrict__ rp,
                         const int* __restrict__ col, const float* __restrict__ dinv,
                         const float* __restrict__ bias, const int* __restrict__ batch,
                         float* __restrict__ hout,
                         float* __restrict__ psum, float* __restrict__ pmax,
                         float* __restrict__ cnt, int n, int store, int do_cnt) {
    int t = blockIdx.x * blockDim.x + threadIdx.x;
    int node = t >> 3, q = t & 7;
    if (node >= n) return;
    int start = (node == 0) ? 0 : rp[node - 1];
    int end = rp[node];
    float dv = dinv[node];

    // self-loop
    float4 acc = *reinterpret_cast<const float4*>(hin + node * F + q * 4);
    float dvv = dv * dv;
    acc.x *= dvv; acc.y *= dvv; acc.z *= dvv; acc.w *= dvv;

    for (int e = start; e < end; ++e) {
        int s = col[e];
        float wv = dinv[s] * dv;
        const float4 v = *reinterpret_cast<const float4*>(hin + s * F + q * 4);
        acc.x += v.x * wv; acc.y += v.y * wv; acc.z += v.z * wv; acc.w += v.w * wv;
    }

    const float4 b4 = *reinterpret_cast<const float4*>(bias + q * 4);
    float4 v;
    v.x = fmaxf(acc.x + b4.x, 0.0f);
    v.y = fmaxf(acc.y + b4.y, 0.0f);
    v.z = fmaxf(acc.z + b4.z, 0.0f);
    v.w = fmaxf(acc.w + b4.w, 0.0f);
    if (store) *reinterpret_cast<float4*>(hout + node * F + q * 4) = v;

    int b = batch[node];
    int lane = threadIdx.x & 63;
    int bFirst = __shfl(b, 0);
    int bLast  = __shfl(b, 63);
    if (bFirst == bLast) {
        // all 8 nodes of this wave in one graph: tree-reduce across node groups
        float4 sv = v, mv = v;
        for (int off = 8; off < 64; off <<= 1) {
            sv.x += __shfl_down(sv.x, off);
            sv.y += __shfl_down(sv.y, off);
            sv.z += __shfl_down(sv.z, off);
            sv.w += __shfl_down(sv.w, off);
            mv.x = fmaxf(mv.x, __shfl_down(mv.x, off));
            mv.y = fmaxf(mv.y, __shfl_down(mv.y, off));
            mv.z = fmaxf(mv.z, __shfl_down(mv.z, off));
            mv.w = fmaxf(mv.w, __shfl_down(mv.w, off));
        }
        if (lane < 8) {
            float* ps = psum + b * F + lane * 4;
            atomicAdd(ps + 0, sv.x);
            atomicAdd(ps + 1, sv.y);
            atomicAdd(ps + 2, sv.z);
            atomicAdd(ps + 3, sv.w);
            int* pm = reinterpret_cast<int*>(pmax + b * F + lane * 4);
            atomicMax(pm + 0, __float_as_int(mv.x));
            atomicMax(pm + 1, __float_as_int(mv.y));
            atomicMax(pm + 2, __float_as_int(mv.z));
            atomicMax(pm + 3, __float_as_int(mv.w));
            if (do_cnt && lane == 0) atomicAdd(&cnt[b], 8.0f);
        }
    } else {
        float* ps = psum + b * F + q * 4;
        atomicAdd(ps + 0, v.x);
        atomicAdd(ps + 1, v.y);
        atomicAdd(ps + 2, v.z);
        atomicAdd(ps + 3, v.w);
        int* pm = reinterpret_cast<int*>(pmax + b * F + q * 4);
        atomicMax(pm + 0, __float_as_int(v.x));
        atomicMax(pm + 1, __float_as_int(v.y));
        atomicMax(pm + 2, __float_as_int(v.z));
        atomicMax(pm + 3, __float_as_int(v.w));
        if (do_cnt && q == 0) atomicAdd(&cnt[b], 1.0f);
    }
}

// ---- MLP head ----
__global__ void k_mlp1(const float* __restrict__ sum1, const float* __restrict__ max1,
                       const float* __restrict__ sum2, const float* __restrict__ max2,
                       const float* __restrict__ cnt,
                       const float* __restrict__ LW1, const float* __restrict__ Lb1,
                       float* __restrict__ z, int nb) {
    int t = blockIdx.x * blockDim.x + threadIdx.x;
    if (t >= nb * POOLD) return;
    int b = t >> 6, j = t & (POOLD - 1);
    float invc = 1.0f / fmaxf(cnt[b], 1.0f);
    float acc = Lb1[j];
#pragma unroll
    for (int i = 0; i < POOLD; ++i) {
        float s;
        if (i < F) s = max1[b * F + i] + max2[b * F + i];
        else       s = (sum1[b * F + i - F] + sum2[b * F + i - F]) * invc;
        acc += s * LW1[i * POOLD + j];
    }
    z[t] = fmaxf(acc, 0.0f);
}

__global__ void k_mlp2(const float* __restrict__ z, const float* __restrict__ LW2,
                       const float* __restrict__ Lb2, float* __restrict__ out,
                       int nb, int outd) {
    int t = blockIdx.x * blockDim.x + threadIdx.x;
    if (t >= nb * outd) return;
    int b = t / outd, o = t % outd;
    float acc = Lb2[o];
#pragma unroll
    for (int j = 0; j < POOLD; ++j) acc += z[b * POOLD + j] * LW2[j * outd + o];
    out[t] = acc;
}

extern "C" void kernel_launch(void* const* d_in, const int* in_sizes, int n_in,
                              void* d_out, int out_size, void* d_ws, size_t ws_size,
                              hipStream_t stream) {
    const float* x    = (const float*)d_in[0];
    const int*   ei   = (const int*)d_in[1];
    const int*   batch= (const int*)d_in[2];
    const float* W1   = (const float*)d_in[3];
    const float* b1   = (const float*)d_in[4];
    const float* W2   = (const float*)d_in[5];
    const float* b2   = (const float*)d_in[6];
    const float* LW1  = (const float*)d_in[7];
    const float* Lb1  = (const float*)d_in[8];
    const float* LW2  = (const float*)d_in[9];
    const float* Lb2  = (const float*)d_in[10];
    float* out = (float*)d_out;

    const int N = in_sizes[0] / 3;
    const int E = in_sizes[1] / 2;
    const int OUTD = in_sizes[10];
    const int B = out_size / OUTD;

    // ---- workspace layout ----
    char* p = (char*)d_ws;
    int* counts = (int*)p;            p += (size_t)N * 4;
    int* rowptr = (int*)p;            p += (size_t)N * 4;
    int* col    = (int*)p;            p += (size_t)E * 4;
    int* partial= (int*)p;            p += 256 * 4;
    float* dinv = (float*)p;          p += (size_t)N * 4;
    float* buf0 = (float*)p;          p += (size_t)N * F * 4;
    float* buf1 = (float*)p;          p += (size_t)N * F * 4;
    float* pools= (float*)p;
    float* sum1 = pools;              // [B*F]
    float* max1 = sum1 + B * F;
    float* sum2 = max1 + B * F;
    float* max2 = sum2 + B * F;
    float* cnt  = max2 + B * F;       // [B]
    float* z    = cnt + B;            // [B*POOLD]
    const int poolsz = 4 * B * F + B;

    const int BS = 256;
    auto g1 = [&](long long n) { return (int)((n + BS - 1) / BS); };
    const int nScanBlocks = (N + SCAN_CHUNK - 1) / SCAN_CHUNK;

    // CSR build + norms
    k_init<<<g1(N > poolsz ? N : poolsz), BS, 0, stream>>>(counts, pools, N, poolsz);
    k_hist<<<g1(E), BS, 0, stream>>>(ei, counts, E);
    k_dinv<<<g1(N), BS, 0, stream>>>(counts, dinv, N);
    k_scan1<<<nScanBlocks, 256, 0, stream>>>(counts, rowptr, partial, N);
    k_scan2<<<1, 256, 0, stream>>>(partial, nScanBlocks);
    k_scan3<<<nScanBlocks, 256, 0, stream>>>(rowptr, partial, N);
    k_place<<<g1(E), BS, 0, stream>>>(ei, rowptr, col, E);   // rowptr -> row ends

    // layer 1
    k_xw1<<<g1((long long)N * F), BS, 0, stream>>>(x, W1, buf0, N);
    k_gather<<<g1((long long)N * 8), BS, 0, stream>>>(buf0, rowptr, col, dinv, b1,
                                                      batch, buf1, sum1, max1, cnt,
                                                      N, /*store=*/1, /*do_cnt=*/1);
    // layer 2
    k_gemm2<<<g1((long long)N * F), BS, 0, stream>>>(buf1, W2, buf0, N);
    k_gather<<<g1((long long)N * 8), BS, 0, stream>>>(buf0, rowptr, col, dinv, b2,
                                                      batch, buf1, sum2, max2, cnt,
                                                      N, /*store=*/0, /*do_cnt=*/0);

    // MLP head
    k_mlp1<<<g1(B * POOLD), BS, 0, stream>>>(sum1, max1, sum2, max2, cnt,
                                             LW1, Lb1, z, B);
    k_mlp2<<<g1(B * OUTD), BS, 0, stream>>>(z, LW2, Lb2, out, B, OUTD);
}